// Round 3
// baseline (591.688 us; speedup 1.0000x reference)
//
#include <hip/hip_runtime.h>

#define NN 100000
#define NE 600000
#define DD 128

typedef __attribute__((ext_vector_type(8))) short bf16x8;   // 8 bf16 in 4 VGPRs
typedef __attribute__((ext_vector_type(4))) float f32x4;

__device__ __forceinline__ ushort f2bf(float f) {   // round-to-nearest-even
  uint u = __float_as_uint(f);
  return (ushort)((u + 0x7FFF + ((u >> 16) & 1)) >> 16);
}
__device__ __forceinline__ float bf2f(ushort h) { return __uint_as_float(((uint)h) << 16); }

// ---------------- CSR build + W prep ----------------

// zero cnt[NN]; also split/transpose W,W_out into bf16 hi/lo [n][k]
__global__ __launch_bounds__(256) void zero_wprep(int* __restrict__ cnt,
                                                  const float* __restrict__ W, const float* __restrict__ Wo,
                                                  ushort* __restrict__ WTh, ushort* __restrict__ WTl,
                                                  ushort* __restrict__ WToh, ushort* __restrict__ WTol) {
  int i = blockIdx.x * 256 + threadIdx.x;
  if (i < NN) cnt[i] = 0;
  int j = i - NN;
  if (j >= 0 && j < 32768) {
    int q = j & 16383;
    int k = q >> 7, n = q & 127;
    float w = (j < 16384) ? W[q] : Wo[q];
    ushort h = f2bf(w);
    ushort lo = f2bf(w - bf2f(h));
    int o = n * 128 + k;
    if (j < 16384) { WTh[o] = h; WTl[o] = lo; }
    else           { WToh[o] = h; WTol[o] = lo; }
  }
}

__global__ __launch_bounds__(256) void count_deg(const int* __restrict__ dst, int* __restrict__ cnt) {
  int e = blockIdx.x * 256 + threadIdx.x;
  if (e < NE) atomicAdd(&cnt[dst[e]], 1);
}

__global__ __launch_bounds__(1024) void scan_partial(const int* __restrict__ cnt,
                                                     int* __restrict__ rowptr,
                                                     int* __restrict__ bsum) {
  __shared__ int tmp[2][1024];
  int t = threadIdx.x;
  int g = blockIdx.x * 1024 + t;
  int v = (g < NN) ? cnt[g] : 0;
  tmp[0][t] = v;
  __syncthreads();
  int pb = 0;
  for (int off = 1; off < 1024; off <<= 1) {
    int nv = tmp[pb][t] + ((t >= off) ? tmp[pb][t - off] : 0);
    tmp[1 - pb][t] = nv;
    pb ^= 1;
    __syncthreads();
  }
  int incl = tmp[pb][t];
  if (g < NN) rowptr[g] = incl - v;   // exclusive
  if (t == 1023) bsum[blockIdx.x] = incl;
}

__global__ __launch_bounds__(128) void scan_sums(int* __restrict__ bsum, int nb) {
  __shared__ int s[128];
  int t = threadIdx.x;
  s[t] = (t < nb) ? bsum[t] : 0;
  __syncthreads();
  if (t == 0) {
    int run = 0;
    for (int j = 0; j < nb; ++j) { int v = s[j]; s[j] = run; run += v; }
  }
  __syncthreads();
  if (t < nb) bsum[t] = s[t];
}

__global__ __launch_bounds__(256) void scan_add(int* __restrict__ rowptr, const int* __restrict__ bsum) {
  int g = blockIdx.x * 256 + threadIdx.x;
  if (g < NN) rowptr[g] += bsum[g >> 10];
  if (g == 0) rowptr[NN] = NE;
}

// cnt holds per-node counts; consume it as a countdown cursor (order within a row
// is arbitrary -> fp32 sum reorder, well inside tolerance)
__global__ __launch_bounds__(256) void fill_csr(const int* __restrict__ src, const int* __restrict__ dst,
                                                const int* __restrict__ rowptr, int* __restrict__ cur,
                                                int* __restrict__ srcidx) {
  int e = blockIdx.x * 256 + threadIdx.x;
  if (e < NE) {
    int d = dst[e];
    int pos = atomicSub(&cur[d], 1) - 1;
    srcidx[rowptr[d] + pos] = src[e];
  }
}

// ---------------- fused layer: gather-sum -> LDS(bf16 hi/lo) -> MFMA -> y_out ----------------
// 512 thr = 8 waves, 128 dst rows/block. LDS 64KB -> 2 blocks/CU.
// Gather: 16 groups x 32 lanes, 8 rows each; lane owns features lane*4..+3.
// LDS layout [row][k] bf16, XOR-swizzle byte ^= (row&7)<<4 (both sides).
// GEMM: wave w owns rows w*16..+15; A-frags from LDS, W-frags (B) from global (L2-resident).
// 3-term hi/lo MFMA (AhBh + AhBl + AlBh). LAST: relu(y3) -> LDS -> second MFMA with W_out.

template <bool LAST>
__global__ __launch_bounds__(512, 4) void layer_fused(
    const float* __restrict__ yin,
    const int* __restrict__ rowptr, const int* __restrict__ srcidx,
    const ushort* __restrict__ Bh, const ushort* __restrict__ Bl,
    const float* __restrict__ bias,
    const ushort* __restrict__ B2h, const ushort* __restrict__ B2l,
    const float* __restrict__ bias2,
    float* __restrict__ yout) {
  __shared__ ushort AH[128 * 128];   // 32 KB
  __shared__ ushort AL[128 * 128];   // 32 KB
  int t  = threadIdx.x;
  int m0 = blockIdx.x * 128;

  // ---- gather phase ----
  {
    int gp = t >> 5, lane = t & 31;
    for (int rr = 0; rr < 8; ++rr) {
      int row  = gp * 8 + rr;
      int node = m0 + row;
      float4 a0 = make_float4(0.f, 0.f, 0.f, 0.f);
      float4 a1 = make_float4(0.f, 0.f, 0.f, 0.f);
      if (node < NN) {
        int beg = rowptr[node], end = rowptr[node + 1];
        int j = beg;
        for (; j + 2 <= end; j += 2) {
          int s0 = srcidx[j], s1 = srcidx[j + 1];
          float4 v0 = *(const float4*)(yin + (size_t)s0 * DD + lane * 4);
          float4 v1 = *(const float4*)(yin + (size_t)s1 * DD + lane * 4);
          a0.x += v0.x; a0.y += v0.y; a0.z += v0.z; a0.w += v0.w;
          a1.x += v1.x; a1.y += v1.y; a1.z += v1.z; a1.w += v1.w;
        }
        if (j < end) {
          int s0 = srcidx[j];
          float4 v0 = *(const float4*)(yin + (size_t)s0 * DD + lane * 4);
          a0.x += v0.x; a0.y += v0.y; a0.z += v0.z; a0.w += v0.w;
        }
      }
      float v[4] = {a0.x + a1.x, a0.y + a1.y, a0.z + a1.z, a0.w + a1.w};
      ushort h[4], l[4];
      #pragma unroll
      for (int r = 0; r < 4; ++r) { h[r] = f2bf(v[r]); l[r] = f2bf(v[r] - bf2f(h[r])); }
      uint2 hh, ll;
      hh.x = (uint)h[0] | ((uint)h[1] << 16); hh.y = (uint)h[2] | ((uint)h[3] << 16);
      ll.x = (uint)l[0] | ((uint)l[1] << 16); ll.y = (uint)l[2] | ((uint)l[3] << 16);
      int boff = row * 256 + ((lane * 8) ^ ((row & 7) << 4));
      *(uint2*)((char*)AH + boff) = hh;
      *(uint2*)((char*)AL + boff) = ll;
    }
  }
  __syncthreads();

  // ---- GEMM phase ----
  int w = t >> 6, l = t & 63;
  int lrow = l & 15, g = l >> 4;
  int rbase = w * 16;

  bf16x8 ah[4], al[4];
  #pragma unroll
  for (int kb = 0; kb < 4; ++kb) {
    int row  = rbase + lrow;
    int boff = row * 256 + ((kb * 64 + g * 16) ^ ((row & 7) << 4));
    ah[kb] = *(const bf16x8*)((char*)AH + boff);
    al[kb] = *(const bf16x8*)((char*)AL + boff);
  }
  f32x4 acc[8];
  #pragma unroll
  for (int ct = 0; ct < 8; ++ct) acc[ct] = (f32x4){0.f, 0.f, 0.f, 0.f};

  #pragma unroll
  for (int ct = 0; ct < 8; ++ct) {
    int nrow = ct * 16 + lrow;     // W output-col
    #pragma unroll
    for (int kb = 0; kb < 4; ++kb) {
      bf16x8 bh = *(const bf16x8*)(Bh + (size_t)nrow * 128 + kb * 32 + g * 8);
      bf16x8 bl = *(const bf16x8*)(Bl + (size_t)nrow * 128 + kb * 32 + g * 8);
      acc[ct] = __builtin_amdgcn_mfma_f32_16x16x32_bf16(ah[kb], bh, acc[ct], 0, 0, 0);
      acc[ct] = __builtin_amdgcn_mfma_f32_16x16x32_bf16(ah[kb], bl, acc[ct], 0, 0, 0);
      acc[ct] = __builtin_amdgcn_mfma_f32_16x16x32_bf16(al[kb], bh, acc[ct], 0, 0, 0);
    }
  }

  if (!LAST) {
    // epilogue: y_out[row][col] = relu(acc + b); C layout: col=lrow, row=g*4+r
    #pragma unroll
    for (int ct = 0; ct < 8; ++ct) {
      float bb = bias[ct * 16 + lrow];
      #pragma unroll
      for (int r = 0; r < 4; ++r) {
        int row = m0 + rbase + g * 4 + r;
        if (row < NN) {
          float v = fmaxf(acc[ct][r] + bb, 0.f);
          yout[(size_t)row * DD + ct * 16 + lrow] = v;
        }
      }
    }
  } else {
    // relu(y3) -> LDS (hi/lo, swizzled), then second MFMA with W_out
    __syncthreads();   // all A-frag reads complete before overwrite
    #pragma unroll
    for (int ct = 0; ct < 8; ++ct) {
      float bb = bias[ct * 16 + lrow];
      #pragma unroll
      for (int r = 0; r < 4; ++r) {
        float v = fmaxf(acc[ct][r] + bb, 0.f);
        ushort h  = f2bf(v);
        ushort lo = f2bf(v - bf2f(h));
        int row  = rbase + g * 4 + r;
        int boff = row * 256 + (((ct * 16 + lrow) * 2) ^ ((row & 7) << 4));
        *(ushort*)((char*)AH + boff) = h;
        *(ushort*)((char*)AL + boff) = lo;
      }
    }
    __syncthreads();

    f32x4 acc2[8];
    #pragma unroll
    for (int ct = 0; ct < 8; ++ct) acc2[ct] = (f32x4){0.f, 0.f, 0.f, 0.f};
    #pragma unroll
    for (int ct = 0; ct < 8; ++ct) {
      int nrow = ct * 16 + lrow;
      #pragma unroll
      for (int kb = 0; kb < 4; ++kb) {
        int row  = rbase + lrow;
        int boff = row * 256 + ((kb * 64 + g * 16) ^ ((row & 7) << 4));
        bf16x8 ch = *(const bf16x8*)((char*)AH + boff);
        bf16x8 cl = *(const bf16x8*)((char*)AL + boff);
        bf16x8 bh = *(const bf16x8*)(B2h + (size_t)nrow * 128 + kb * 32 + g * 8);
        bf16x8 bl = *(const bf16x8*)(B2l + (size_t)nrow * 128 + kb * 32 + g * 8);
        acc2[ct] = __builtin_amdgcn_mfma_f32_16x16x32_bf16(ch, bh, acc2[ct], 0, 0, 0);
        acc2[ct] = __builtin_amdgcn_mfma_f32_16x16x32_bf16(ch, bl, acc2[ct], 0, 0, 0);
        acc2[ct] = __builtin_amdgcn_mfma_f32_16x16x32_bf16(cl, bh, acc2[ct], 0, 0, 0);
      }
    }
    #pragma unroll
    for (int ct = 0; ct < 8; ++ct) {
      float bb = bias2[ct * 16 + lrow];
      #pragma unroll
      for (int r = 0; r < 4; ++r) {
        int row = m0 + rbase + g * 4 + r;
        if (row < NN) yout[(size_t)row * DD + ct * 16 + lrow] = acc2[ct][r] + bb;
      }
    }
  }
}

// ---------------- launch ----------------

extern "C" void kernel_launch(void* const* d_in, const int* in_sizes, int n_in,
                              void* d_out, int out_size, void* d_ws, size_t ws_size,
                              hipStream_t stream) {
  const float* x     = (const float*)d_in[0];
  const int*   ei    = (const int*)d_in[1];
  const float* W     = (const float*)d_in[2];
  const float* b     = (const float*)d_in[3];
  const float* W_out = (const float*)d_in[4];
  const float* b_out = (const float*)d_in[5];
  float*       out   = (float*)d_out;

  const int* src = ei;
  const int* dst = ei + NE;

  char* ws = (char*)d_ws;
  int*    rowptr = (int*)(ws + 0);            //  400128 B
  int*    cnt    = (int*)(ws + 400128);       //  400128 B
  int*    bsum   = (int*)(ws + 800256);       //    2048 B
  int*    srcidx = (int*)(ws + 802304);       // 2400000 B
  ushort* WTh    = (ushort*)(ws + 3202304);   //   32768 B each
  ushort* WTl    = (ushort*)(ws + 3235072);
  ushort* WToh   = (ushort*)(ws + 3267840);
  ushort* WTol   = (ushort*)(ws + 3300608);
  float*  yf1    = (float*)(ws + 3333376);    // 51.2 MB
  float*  yf2    = (float*)(ws + 54533376);   // 51.2 MB
  // total 105,733,376 B

  const int nb_scan = (NN + 1023) / 1024;     // 98

  zero_wprep<<<(NN + 32768 + 255) / 256, 256, 0, stream>>>(cnt, W, W_out, WTh, WTl, WToh, WTol);
  count_deg<<<(NE + 255) / 256, 256, 0, stream>>>(dst, cnt);
  scan_partial<<<nb_scan, 1024, 0, stream>>>(cnt, rowptr, bsum);
  scan_sums<<<1, 128, 0, stream>>>(bsum, nb_scan);
  scan_add<<<(NN + 255) / 256, 256, 0, stream>>>(rowptr, bsum);
  fill_csr<<<(NE + 255) / 256, 256, 0, stream>>>(src, dst, rowptr, cnt, srcidx);

  const int lblocks = (NN + 127) / 128;       // 782

  layer_fused<false><<<lblocks, 512, 0, stream>>>(x,   rowptr, srcidx, WTh, WTl, b,
                                                  nullptr, nullptr, nullptr, yf1);
  layer_fused<false><<<lblocks, 512, 0, stream>>>(yf1, rowptr, srcidx, WTh, WTl, b,
                                                  nullptr, nullptr, nullptr, yf2);
  layer_fused<true><<<lblocks, 512, 0, stream>>>(yf2, rowptr, srcidx, WTh, WTl, b,
                                                 WToh, WTol, b_out, out);
}